// Round 1
// baseline (1176.473 us; speedup 1.0000x reference)
//
#include <hip/hip_runtime.h>

#define BATCH 8
#define CCH   128
#define DQK   16
#define HW    4096   // N = H*W

// ------------------------------------------------------------------
// Kernel A: q/k/v 1x1 conv projections.
// grid = BATCH * (HW/64) = 512 blocks, 256 threads.
// Wave g (=tid/64) computes output channels o = g*40 .. g*40+39 of the
// stacked [160,128] weight (rows 0..15 = Wq, 16..31 = Wk, 32..159 = Wv).
// K staged in 4 chunks of 32 to keep LDS < 32 KB.
// ------------------------------------------------------------------
__global__ __launch_bounds__(256) void qkv_kernel(
    const float* __restrict__ x,
    const float* __restrict__ Wq, const float* __restrict__ bq,
    const float* __restrict__ Wk, const float* __restrict__ bk,
    const float* __restrict__ Wv, const float* __restrict__ bv,
    float* __restrict__ q, float* __restrict__ k, float* __restrict__ v)
{
    const int blk = blockIdx.x;
    const int b   = blk >> 6;          // 64 pixel-tiles per batch
    const int p0  = (blk & 63) << 6;
    const int t   = threadIdx.x;
    const int p   = t & 63;
    const int g   = t >> 6;            // wave id 0..3

    __shared__ float Wl[160 * 32];     // W chunk [160][32]
    __shared__ float Xl[32][64];       // x chunk [32 c][64 pix]

    float acc[40];
#pragma unroll
    for (int i = 0; i < 40; i++) acc[i] = 0.f;

    for (int cc = 0; cc < CCH; cc += 32) {
        __syncthreads();   // protect previous chunk's reads
        // stage W chunk: 160*32 = 5120 floats
        for (int idx = t; idx < 5120; idx += 256) {
            const int row = idx >> 5, col = idx & 31;
            float w;
            if (row < 16)       w = Wq[row * CCH + cc + col];
            else if (row < 32)  w = Wk[(row - 16) * CCH + cc + col];
            else                w = Wv[(row - 32) * CCH + cc + col];
            Wl[idx] = w;
        }
        // stage x chunk: 32*64 floats, coalesced on pixel
        for (int idx = t; idx < 2048; idx += 256) {
            const int row = idx >> 6, col = idx & 63;
            Xl[row][col] = x[((size_t)(b * CCH + cc + row)) * HW + p0 + col];
        }
        __syncthreads();

        for (int c4 = 0; c4 < 8; c4++) {
            const float xv0 = Xl[c4 * 4 + 0][p];
            const float xv1 = Xl[c4 * 4 + 1][p];
            const float xv2 = Xl[c4 * 4 + 2][p];
            const float xv3 = Xl[c4 * 4 + 3][p];
#pragma unroll
            for (int kk = 0; kk < 40; kk++) {
                const float4 w4 = *(const float4*)&Wl[(g * 40 + kk) * 32 + c4 * 4];
                acc[kk] += w4.x * xv0 + w4.y * xv1 + w4.z * xv2 + w4.w * xv3;
            }
        }
    }

#pragma unroll
    for (int kk = 0; kk < 40; kk++) {
        const int o = g * 40 + kk;
        float bias, *dst;
        if (o < 16)      { bias = bq[o];       dst = &q[((size_t)(b * DQK + o))        * HW + p0 + p]; }
        else if (o < 32) { bias = bk[o - 16];  dst = &k[((size_t)(b * DQK + (o - 16))) * HW + p0 + p]; }
        else             { bias = bv[o - 32];  dst = &v[((size_t)(b * CCH + (o - 32))) * HW + p0 + p]; }
        *dst = acc[kk] + bias;
    }
}

// ------------------------------------------------------------------
// Kernel B: flash attention + gamma*out + x epilogue.
// grid = BATCH * (HW/64) = 512 blocks, 256 threads (4 waves).
// Block owns 64 query rows (i0..i0+63); loops 64 j-tiles of width 64.
// Thread PV mapping: i = lane, c = wave + 4*kk (kk<32) -> 32 fp32 acc.
// ------------------------------------------------------------------
__global__ __launch_bounds__(256) void attn_kernel(
    const float* __restrict__ q, const float* __restrict__ k,
    const float* __restrict__ v, const float* __restrict__ x,
    const float* __restrict__ gamma, float* __restrict__ out)
{
    const int blk  = blockIdx.x;
    const int b    = blk >> 6;
    const int i0   = (blk & 63) << 6;
    const int t    = threadIdx.x;
    const int lane = t & 63;
    const int w    = t >> 6;

    __shared__ float qT[64][16];    // q transposed: [i][d]
    __shared__ float kl[16][64];    // [d][j]
    __shared__ float vl[128][64];   // [c][j]
    __shared__ float P[64][68];     // scores / probs, padded
    __shared__ float m_s[64], l_s[64], alpha_s[64];

    // load q tile (once per block), transposed for float4 broadcast reads
    for (int idx = t; idx < 1024; idx += 256) {
        const int d = idx >> 6, i = idx & 63;
        qT[i][d] = q[((size_t)(b * DQK + d)) * HW + i0 + i];
    }
    if (t < 64) { m_s[t] = -1e30f; l_s[t] = 0.f; }

    float acc[32];
#pragma unroll
    for (int kk = 0; kk < 32; kk++) acc[kk] = 0.f;
    __syncthreads();

    for (int j0 = 0; j0 < HW; j0 += 64) {
        // ---- stage k,v tiles (coalesced on j) ----
        for (int idx = t; idx < 1024; idx += 256) {
            const int d = idx >> 6, j = idx & 63;
            kl[d][j] = k[((size_t)(b * DQK + d)) * HW + j0 + j];
        }
        for (int idx = t; idx < 8192; idx += 256) {
            const int c = idx >> 6, j = idx & 63;
            vl[c][j] = v[((size_t)(b * CCH + c)) * HW + j0 + j];
        }
        __syncthreads();

        // ---- S = q^T k : thread does j = lane, rows i = w*16..w*16+15 ----
        {
            const int j = lane;
            float kcol[16];
#pragma unroll
            for (int d = 0; d < 16; d++) kcol[d] = kl[d][j];
#pragma unroll
            for (int ii = 0; ii < 16; ii++) {
                const int i = w * 16 + ii;
                const float4* qp = (const float4*)&qT[i][0];
                float s = 0.f;
#pragma unroll
                for (int d4 = 0; d4 < 4; d4++) {
                    const float4 q4 = qp[d4];
                    s += q4.x * kcol[d4 * 4 + 0] + q4.y * kcol[d4 * 4 + 1]
                       + q4.z * kcol[d4 * 4 + 2] + q4.w * kcol[d4 * 4 + 3];
                }
                P[i][j] = s;
            }
        }
        __syncthreads();

        // ---- online softmax: 4 lanes per row, interleaved j = part + 4*jj ----
        {
            const int i = t >> 2, part = t & 3;
            float mx = -1e30f;
#pragma unroll
            for (int jj = 0; jj < 16; jj++) mx = fmaxf(mx, P[i][part + jj * 4]);
            mx = fmaxf(mx, __shfl_xor(mx, 1));
            mx = fmaxf(mx, __shfl_xor(mx, 2));
            const float m_old = m_s[i];
            const float m_new = fmaxf(m_old, mx);
            float sum = 0.f;
#pragma unroll
            for (int jj = 0; jj < 16; jj++) {
                const float pv = __expf(P[i][part + jj * 4] - m_new);
                P[i][part + jj * 4] = pv;
                sum += pv;
            }
            sum += __shfl_xor(sum, 1);
            sum += __shfl_xor(sum, 2);
            if (part == 0) {
                const float alpha = __expf(m_old - m_new);
                l_s[i]    = l_s[i] * alpha + sum;
                m_s[i]    = m_new;
                alpha_s[i] = alpha;
            }
        }
        __syncthreads();

        // ---- PV accumulate: i = lane, c = w + 4*kk ----
        {
            const int i = lane;
            const float al = alpha_s[i];
#pragma unroll
            for (int kk = 0; kk < 32; kk++) acc[kk] *= al;
            const float4* Pp = (const float4*)&P[i][0];
            for (int jj = 0; jj < 16; jj++) {
                const float4 p4 = Pp[jj];
#pragma unroll
                for (int kk = 0; kk < 32; kk++) {
                    const int c = w + kk * 4;
                    const float4 v4 = ((const float4*)&vl[c][0])[jj];
                    acc[kk] += p4.x * v4.x + p4.y * v4.y + p4.z * v4.z + p4.w * v4.w;
                }
            }
        }
        __syncthreads();
    }

    // ---- epilogue: out = gamma * (acc/l) + x ----
    {
        const int i = lane;
        const float linv = 1.f / l_s[i];
        const float gm = gamma[0];
#pragma unroll
        for (int kk = 0; kk < 32; kk++) {
            const int c = w + kk * 4;
            const size_t off = ((size_t)(b * CCH + c)) * HW + i0 + i;
            out[off] = gm * (acc[kk] * linv) + x[off];
        }
    }
}

extern "C" void kernel_launch(void* const* d_in, const int* in_sizes, int n_in,
                              void* d_out, int out_size, void* d_ws, size_t ws_size,
                              hipStream_t stream)
{
    const float* x     = (const float*)d_in[0];
    const float* Wq    = (const float*)d_in[1];
    const float* bq    = (const float*)d_in[2];
    const float* Wk    = (const float*)d_in[3];
    const float* bk    = (const float*)d_in[4];
    const float* Wv    = (const float*)d_in[5];
    const float* bv    = (const float*)d_in[6];
    const float* gamma = (const float*)d_in[7];
    float* out = (float*)d_out;

    float* q = (float*)d_ws;                        // [8][16][4096]
    float* k = q + (size_t)BATCH * DQK * HW;        // [8][16][4096]
    float* v = k + (size_t)BATCH * DQK * HW;        // [8][128][4096]

    qkv_kernel<<<dim3(BATCH * (HW / 64)), dim3(256), 0, stream>>>(
        x, Wq, bq, Wk, bk, Wv, bv, q, k, v);
    attn_kernel<<<dim3(BATCH * (HW / 64)), dim3(256), 0, stream>>>(
        q, k, v, x, gamma, out);
}

// Round 2
// 251.519 us; speedup vs baseline: 4.6775x; 4.6775x over previous
//
#include <hip/hip_runtime.h>

#define BATCH 8
#define CCH   128
#define DQK   16
#define HW    4096   // N = H*W

typedef __attribute__((ext_vector_type(8))) short bf16x8;   // 8 bf16 = 4 VGPRs
typedef __attribute__((ext_vector_type(4))) float f32x4;

__device__ __forceinline__ ushort f2bf(float f) {
    union { float f; unsigned u; } v; v.f = f;
    unsigned u = v.u;
    u += 0x7fffu + ((u >> 16) & 1u);   // round-to-nearest-even
    return (ushort)(u >> 16);
}

// ------------------------------------------------------------------
// Kernel A: q/k/v 1x1 conv projections -> bf16.
// q,k stored TRANSPOSED: qT/kT[b][pixel][16] so attn frag loads are
// contiguous. v stored [b][c][pixel].
// grid = 512 blocks x 256 threads; wave g owns channels g*40..g*40+39
// of stacked [160,128] weights (0..15=Wq, 16..31=Wk, 32..159=Wv).
// ------------------------------------------------------------------
__global__ __launch_bounds__(256) void qkv_kernel(
    const float* __restrict__ x,
    const float* __restrict__ Wq, const float* __restrict__ bq,
    const float* __restrict__ Wk, const float* __restrict__ bk,
    const float* __restrict__ Wv, const float* __restrict__ bv,
    ushort* __restrict__ qT, ushort* __restrict__ kT, ushort* __restrict__ v)
{
    const int blk = blockIdx.x;
    const int b   = blk >> 6;
    const int p0  = (blk & 63) << 6;
    const int t   = threadIdx.x;
    const int p   = t & 63;
    const int g   = t >> 6;

    __shared__ float Wl[160 * 32];
    __shared__ float Xl[32][64];

    float acc[40];
#pragma unroll
    for (int i = 0; i < 40; i++) acc[i] = 0.f;

    for (int cc = 0; cc < CCH; cc += 32) {
        __syncthreads();
        for (int idx = t; idx < 5120; idx += 256) {
            const int row = idx >> 5, col = idx & 31;
            float w;
            if (row < 16)       w = Wq[row * CCH + cc + col];
            else if (row < 32)  w = Wk[(row - 16) * CCH + cc + col];
            else                w = Wv[(row - 32) * CCH + cc + col];
            Wl[idx] = w;
        }
        for (int idx = t; idx < 2048; idx += 256) {
            const int row = idx >> 6, col = idx & 63;
            Xl[row][col] = x[((size_t)(b * CCH + cc + row)) * HW + p0 + col];
        }
        __syncthreads();

        for (int c4 = 0; c4 < 8; c4++) {
            const float xv0 = Xl[c4 * 4 + 0][p];
            const float xv1 = Xl[c4 * 4 + 1][p];
            const float xv2 = Xl[c4 * 4 + 2][p];
            const float xv3 = Xl[c4 * 4 + 3][p];
#pragma unroll
            for (int kk = 0; kk < 40; kk++) {
                const float4 w4 = *(const float4*)&Wl[(g * 40 + kk) * 32 + c4 * 4];
                acc[kk] += w4.x * xv0 + w4.y * xv1 + w4.z * xv2 + w4.w * xv3;
            }
        }
    }

#pragma unroll
    for (int kk = 0; kk < 40; kk++) {
        const int o = g * 40 + kk;
        if (o < 16)
            qT[((size_t)(b * HW + p0 + p)) * DQK + o] = f2bf(acc[kk] + bq[o]);
        else if (o < 32)
            kT[((size_t)(b * HW + p0 + p)) * DQK + (o - 16)] = f2bf(acc[kk] + bk[o - 16]);
        else
            v[((size_t)(b * CCH + (o - 32))) * HW + p0 + p] = f2bf(acc[kk] + bv[o - 32]);
    }
}

// ------------------------------------------------------------------
// Kernel B: flash attention, bf16 MFMA 16x16x32.
// grid = 512 blocks x 256 threads (4 waves). Block owns 64 query rows.
// Wave w owns i-range [16w,16w+16): computes S^T = mfma(Kfrag,Qfrag)
// so each lane holds 16 S values all for ONE i (i = i0+16w+(l&15)).
// Online softmax: 16 regs + shfl_xor(16,32). P -> LDS bf16 -> B-frag.
// PV: A=v (8 c-tiles), B=P^T, 2 k-steps of 32 j.
// ------------------------------------------------------------------
__global__ __launch_bounds__(256) void attn_kernel(
    const ushort* __restrict__ qT, const ushort* __restrict__ kTg,
    const ushort* __restrict__ vg, const float* __restrict__ x,
    const float* __restrict__ gamma, float* __restrict__ out)
{
    const int blk = blockIdx.x;
    const int b   = blk >> 6;
    const int i0  = (blk & 63) << 6;
    const int t   = threadIdx.x;
    const int l   = t & 63;
    const int w   = t >> 6;
    const int lm  = l & 15;   // D-layout col; A-row; i-within-tile
    const int lg  = l >> 4;   // lane group (k-quarter)

    __shared__ __align__(16) ushort kT_l[64 * 40];   // [j][40] cols 0-15 = d, 16-31 zero
    __shared__ __align__(16) ushort v_l[128 * 72];   // [c][72] (pad 64->72: b128 conflict-free)
    __shared__ __align__(16) ushort P_l[64 * 72];    // [i][72] bf16 probs

    // zero kT_l cols 16..39 once (MFMA K=32, d padded with zeros)
    for (int idx = t; idx < 64 * 24; idx += 256)
        kT_l[(idx / 24) * 40 + 16 + (idx % 24)] = 0;

    // Q B-frag: lane needs q[d = lg*8+t][i = i0+16w+lm]; lg>=2 -> zeros
    bf16x8 qf;
#pragma unroll
    for (int z = 0; z < 8; z++) qf[z] = 0;
    if (lg < 2) {
        const size_t qoff = ((size_t)(b * HW + i0 + 16 * w + lm)) * DQK + lg * 8;
        qf = *reinterpret_cast<const bf16x8*>(qT + qoff);
    }

    f32x4 zero4;
#pragma unroll
    for (int z = 0; z < 4; z++) zero4[z] = 0.f;

    f32x4 acc[8];
#pragma unroll
    for (int ct = 0; ct < 8; ct++) acc[ct] = zero4;

    float m_i = -1e30f, l_i = 0.f;

    for (int j0 = 0; j0 < HW; j0 += 64) {
        __syncthreads();   // previous tile's kT_l / v_l reads done

        // ---- stage kT tile: 64 rows x 16 d (8B per thread) ----
        {
            const int row = t >> 2, c4 = (t & 3) * 4;
            const size_t src = ((size_t)(b * HW + j0 + row)) * DQK + c4;
            const ushort4 kv = *reinterpret_cast<const ushort4*>(kTg + src);
            *reinterpret_cast<ushort4*>(&kT_l[row * 40 + c4]) = kv;
        }
        // ---- stage v tile: 128 c x 64 j (4 x 16B per thread) ----
#pragma unroll
        for (int it = 0; it < 4; it++) {
            const int idx8 = t + 256 * it;          // unit = 8 ushorts
            const int c = idx8 >> 3, j8 = (idx8 & 7) * 8;
            const size_t src = ((size_t)(b * CCH + c)) * HW + j0 + j8;
            const bf16x8 vv = *reinterpret_cast<const bf16x8*>(vg + src);
            *reinterpret_cast<bf16x8*>(&v_l[c * 72 + j8]) = vv;
        }
        __syncthreads();

        // ---- S^T = mfma(K, Q): s[jt][r] = S[i][j = j0 + jt*16 + lg*4 + r] ----
        f32x4 s[4];
#pragma unroll
        for (int jt = 0; jt < 4; jt++) {
            const bf16x8 kf = *reinterpret_cast<const bf16x8*>(
                &kT_l[(jt * 16 + lm) * 40 + lg * 8]);
            s[jt] = __builtin_amdgcn_mfma_f32_16x16x32_bf16(kf, qf, zero4, 0, 0, 0);
        }

        // ---- online softmax (one i per lane; partners share lm) ----
        float mx = s[0][0];
#pragma unroll
        for (int jt = 0; jt < 4; jt++)
#pragma unroll
            for (int r = 0; r < 4; r++) mx = fmaxf(mx, s[jt][r]);
        mx = fmaxf(mx, __shfl_xor(mx, 16));
        mx = fmaxf(mx, __shfl_xor(mx, 32));
        const float m_new = fmaxf(m_i, mx);
        const float alpha = __expf(m_i - m_new);
        float sum = 0.f;
#pragma unroll
        for (int jt = 0; jt < 4; jt++) {
            float p0f = __expf(s[jt][0] - m_new);
            float p1f = __expf(s[jt][1] - m_new);
            float p2f = __expf(s[jt][2] - m_new);
            float p3f = __expf(s[jt][3] - m_new);
            sum += (p0f + p1f) + (p2f + p3f);
            ushort4 pk;
            pk.x = f2bf(p0f); pk.y = f2bf(p1f); pk.z = f2bf(p2f); pk.w = f2bf(p3f);
            // P[i][j]: row = 16w+lm, col = jt*16 + lg*4
            *reinterpret_cast<ushort4*>(&P_l[(16 * w + lm) * 72 + jt * 16 + lg * 4]) = pk;
        }
        sum += __shfl_xor(sum, 16);
        sum += __shfl_xor(sum, 32);
        l_i = l_i * alpha + sum;
        m_i = m_new;

        // ---- rescale accumulators (alpha is lane-uniform: one i per lane) ----
#pragma unroll
        for (int ct = 0; ct < 8; ct++) acc[ct] *= alpha;

        // ---- PV: acc[ct] += v[c-tile ct] * P^T   (same-wave LDS: in-order) ----
#pragma unroll
        for (int ks = 0; ks < 2; ks++) {
            const bf16x8 pf = *reinterpret_cast<const bf16x8*>(
                &P_l[(16 * w + lm) * 72 + ks * 32 + lg * 8]);
#pragma unroll
            for (int ct = 0; ct < 8; ct++) {
                const bf16x8 vf = *reinterpret_cast<const bf16x8*>(
                    &v_l[(ct * 16 + lm) * 72 + ks * 32 + lg * 8]);
                acc[ct] = __builtin_amdgcn_mfma_f32_16x16x32_bf16(vf, pf, acc[ct], 0, 0, 0);
            }
        }
    }

    // ---- epilogue: out = gamma * (acc / l) + x ----
    const float linv = 1.f / l_i;
    const float gm = gamma[0];
    const int i = 16 * w + lm;
#pragma unroll
    for (int ct = 0; ct < 8; ct++) {
#pragma unroll
        for (int r = 0; r < 4; r++) {
            const int c = ct * 16 + lg * 4 + r;        // D-layout row
            const size_t off = ((size_t)(b * CCH + c)) * HW + i0 + i;
            out[off] = gm * (acc[ct][r] * linv) + x[off];
        }
    }
}

extern "C" void kernel_launch(void* const* d_in, const int* in_sizes, int n_in,
                              void* d_out, int out_size, void* d_ws, size_t ws_size,
                              hipStream_t stream)
{
    const float* x     = (const float*)d_in[0];
    const float* Wq    = (const float*)d_in[1];
    const float* bq    = (const float*)d_in[2];
    const float* Wk    = (const float*)d_in[3];
    const float* bk    = (const float*)d_in[4];
    const float* Wv    = (const float*)d_in[5];
    const float* bv    = (const float*)d_in[6];
    const float* gamma = (const float*)d_in[7];
    float* out = (float*)d_out;

    ushort* qT = (ushort*)d_ws;                          // [8][4096][16] bf16
    ushort* kT = qT + (size_t)BATCH * HW * DQK;          // [8][4096][16] bf16
    ushort* v  = kT + (size_t)BATCH * HW * DQK;          // [8][128][4096] bf16

    qkv_kernel<<<dim3(BATCH * (HW / 64)), dim3(256), 0, stream>>>(
        x, Wq, bq, Wk, bk, Wv, bv, qT, kT, v);
    attn_kernel<<<dim3(BATCH * (HW / 64)), dim3(256), 0, stream>>>(
        qT, kT, v, x, gamma, out);
}

// Round 3
// 187.185 us; speedup vs baseline: 6.2851x; 1.3437x over previous
//
#include <hip/hip_runtime.h>

#define BATCH 8
#define CCH   128
#define DQK   16
#define HW    4096   // N = H*W
#define LOG2E 1.44269504088896340736f

typedef __attribute__((ext_vector_type(8))) short bf16x8;   // 8 bf16 = 4 VGPRs
typedef __attribute__((ext_vector_type(4))) float f32x4;

// pack two f32 -> packed bf16 pair (lo, hi), single HW instruction
__device__ __forceinline__ unsigned cvt_pk_bf16(float lo, float hi) {
    unsigned r;
    asm("v_cvt_pk_bf16_f32 %0, %1, %2" : "=v"(r) : "v"(lo), "v"(hi));
    return r;
}

// ------------------------------------------------------------------
// Kernel A: q/k/v 1x1 conv projections via bf16 MFMA.
// grid = 512 blocks x 256 threads (4 waves). Block owns 64 pixels.
// Stacked weight rows: 0-15 = Wq (x LOG2E), 16-31 = Wk, 32-159 = Wv.
// D[o][pixel] = W[160x128] . x^T ; wave w owns pixel-tile w (16 px),
// loops 10 o-tiles x 4 k-steps = 40 MFMA.
// q,k stored transposed [b][pixel][16]; v stored [b][c][pixel].
// ------------------------------------------------------------------
__global__ __launch_bounds__(256) void qkv_kernel(
    const float* __restrict__ x,
    const float* __restrict__ Wq, const float* __restrict__ bq,
    const float* __restrict__ Wk, const float* __restrict__ bk,
    const float* __restrict__ Wv, const float* __restrict__ bv,
    ushort* __restrict__ qT, ushort* __restrict__ kT, ushort* __restrict__ v)
{
    const int blk = blockIdx.x;
    const int b   = blk >> 6;
    const int p0  = (blk & 63) << 6;
    const int t   = threadIdx.x;
    const int l   = t & 63;
    const int w   = t >> 6;
    const int lm  = l & 15;
    const int lg  = l >> 4;

    // stride 136 ushorts = 272B: 16B-aligned rows, 2-way-free b128 reads
    __shared__ __align__(16) ushort W_l[160 * 136];
    __shared__ __align__(16) ushort xT_l[64 * 136];
    __shared__ float bias_l[160];

    // ---- stage W -> bf16 LDS (row o = w + 4*it; 64 lanes = 64 col-pairs) ----
    for (int it = 0; it < 40; it++) {
        const int o  = w + 4 * it;
        const int c2 = l * 2;
        const float* src;
        float scale = 1.f;
        if (o < 16)      { src = Wq + o * CCH;        scale = LOG2E; }
        else if (o < 32) { src = Wk + (o - 16) * CCH; }
        else             { src = Wv + (o - 32) * CCH; }
        const float2 wv = *(const float2*)(src + c2);
        *(unsigned*)&W_l[o * 136 + c2] = cvt_pk_bf16(wv.x * scale, wv.y * scale);
    }
    if (t < 160) {
        float bb;
        if (t < 16)      bb = bq[t] * LOG2E;
        else if (t < 32) bb = bk[t - 16];
        else             bb = bv[t - 32];
        bias_l[t] = bb;
    }

    // ---- stage x^T tile: lane = pixel, octet oc = w + 4*it ----
#pragma unroll
    for (int it = 0; it < 4; it++) {
        const int oc = w + 4 * it;          // c-octet 0..15
        float xr[8];
#pragma unroll
        for (int r = 0; r < 8; r++)
            xr[r] = x[((size_t)(b * CCH + oc * 8 + r)) * HW + p0 + l];
        unsigned u[4];
#pragma unroll
        for (int r = 0; r < 4; r++) u[r] = cvt_pk_bf16(xr[2 * r], xr[2 * r + 1]);
        *(bf16x8*)&xT_l[l * 136 + oc * 8] = *(bf16x8*)u;
    }
    __syncthreads();

    // ---- MFMA: wave w -> pixels p0 + 16w .. +16 ----
    f32x4 acc[10];
#pragma unroll
    for (int ot = 0; ot < 10; ot++)
#pragma unroll
        for (int r = 0; r < 4; r++) acc[ot][r] = 0.f;

#pragma unroll
    for (int ks = 0; ks < 4; ks++) {
        const bf16x8 bfrag = *(const bf16x8*)&xT_l[(w * 16 + lm) * 136 + ks * 32 + lg * 8];
#pragma unroll
        for (int ot = 0; ot < 10; ot++) {
            const bf16x8 afrag = *(const bf16x8*)&W_l[(ot * 16 + lm) * 136 + ks * 32 + lg * 8];
            acc[ot] = __builtin_amdgcn_mfma_f32_16x16x32_bf16(afrag, bfrag, acc[ot], 0, 0, 0);
        }
    }

    // ---- epilogue: D col=lm -> pixel, row=4lg+r -> o ----
    const int px = p0 + w * 16 + lm;
#pragma unroll
    for (int ot = 0; ot < 10; ot++) {
        const int ob = ot * 16 + 4 * lg;
        const float4 bb = *(const float4*)&bias_l[ob];
        const float r0 = acc[ot][0] + bb.x, r1 = acc[ot][1] + bb.y;
        const float r2 = acc[ot][2] + bb.z, r3 = acc[ot][3] + bb.w;
        const unsigned w0 = cvt_pk_bf16(r0, r1), w1 = cvt_pk_bf16(r2, r3);
        if (ot == 0) {
            uint2 pk; pk.x = w0; pk.y = w1;
            *(uint2*)&qT[((size_t)(b * HW + px)) * DQK + ob] = pk;
        } else if (ot == 1) {
            uint2 pk; pk.x = w0; pk.y = w1;
            *(uint2*)&kT[((size_t)(b * HW + px)) * DQK + (ob - 16)] = pk;
        } else {
            const int c = ob - 32;
            v[((size_t)(b * CCH + c + 0)) * HW + px] = (ushort)(w0 & 0xffff);
            v[((size_t)(b * CCH + c + 1)) * HW + px] = (ushort)(w0 >> 16);
            v[((size_t)(b * CCH + c + 2)) * HW + px] = (ushort)(w1 & 0xffff);
            v[((size_t)(b * CCH + c + 3)) * HW + px] = (ushort)(w1 >> 16);
        }
    }
}

// ------------------------------------------------------------------
// Kernel B: flash attention, bf16 MFMA 16x16x32, KVBLK = 128.
// grid = 512 x 256 (4 waves). Block owns 64 query rows; wave w owns
// i-range [16w,16w+16). Softmax in exp2 domain (log2e folded into q).
// v_l / P_l use 16B-granule XOR swizzle g^=(row&15): PV b128 reads
// and staging writes are 2-way (free). Defer-rescale (T13, THR=8).
// ------------------------------------------------------------------
__global__ __launch_bounds__(256) void attn_kernel(
    const ushort* __restrict__ qT, const ushort* __restrict__ kTg,
    const ushort* __restrict__ vg, const float* __restrict__ x,
    const float* __restrict__ gamma, float* __restrict__ out)
{
    // XCD swizzle: 512 = 8 XCDs x 64; each XCD gets one batch (K/V L2-resident)
    const int blk = ((blockIdx.x & 7) << 6) | (blockIdx.x >> 3);
    const int b   = blk >> 6;
    const int i0  = (blk & 63) << 6;
    const int t   = threadIdx.x;
    const int l   = t & 63;
    const int w   = t >> 6;
    const int lm  = l & 15;   // B-operand lane idx -> D col
    const int lg  = l >> 4;

    __shared__ __align__(16) ushort kT_l[128 * 40];    // [j][40], cols 16-39 zero
    __shared__ __align__(16) ushort v_l [128 * 128];   // [c][128j], XOR-swizzled granules
    __shared__ __align__(16) ushort P_l [64 * 128];    // [i][128j], XOR-swizzled granules

    // zero kT_l cols 16..39 once (QK MFMA K=32, d zero-padded)
    for (int idx = t; idx < 128 * 24; idx += 256)
        kT_l[(idx / 24) * 40 + 16 + (idx % 24)] = 0;

    // Q B-frag (log2e pre-folded): lane needs q[i = i0+16w+lm][d = lg*8..]; lg>=2 zero
    bf16x8 qf;
#pragma unroll
    for (int z = 0; z < 8; z++) qf[z] = 0;
    if (lg < 2)
        qf = *(const bf16x8*)(qT + ((size_t)(b * HW + i0 + 16 * w + lm)) * DQK + lg * 8);

    f32x4 zero4;
#pragma unroll
    for (int z = 0; z < 4; z++) zero4[z] = 0.f;

    f32x4 acc[8];
#pragma unroll
    for (int ct = 0; ct < 8; ct++) acc[ct] = zero4;

    float m_i = -1e30f, l_i = 0.f;

    for (int j0 = 0; j0 < HW; j0 += 128) {
        __syncthreads();   // previous tile fully consumed

        // ---- stage kT tile: 128 rows x 16 d; 1 b128 per thread ----
        {
            const int row = t >> 1, c8 = (t & 1) * 8;
            *(bf16x8*)&kT_l[row * 40 + c8] =
                *(const bf16x8*)(kTg + ((size_t)(b * HW + j0 + row)) * DQK + c8);
        }
        // ---- stage v tile: 128c x 128j, swizzled; 8 b128 per thread ----
#pragma unroll
        for (int it = 0; it < 8; it++) {
            const int idx = t + 256 * it;
            const int c = idx >> 4, gj = idx & 15;
            const int g = gj ^ (c & 15);
            *(bf16x8*)&v_l[c * 128 + g * 8] =
                *(const bf16x8*)(vg + ((size_t)(b * CCH + c)) * HW + j0 + gj * 8);
        }
        __syncthreads();

        // ---- S^T = mfma(K,Q): s[jt][r] = S[i][j = j0 + jt*16 + lg*4 + r] (exp2 dom) ----
        f32x4 s[8];
#pragma unroll
        for (int jt = 0; jt < 8; jt++) {
            const bf16x8 kf = *(const bf16x8*)&kT_l[(jt * 16 + lm) * 40 + lg * 8];
            s[jt] = __builtin_amdgcn_mfma_f32_16x16x32_bf16(kf, qf, zero4, 0, 0, 0);
        }

        // ---- online softmax, one i per lane ----
        float mx = s[0][0];
#pragma unroll
        for (int jt = 0; jt < 8; jt++)
#pragma unroll
            for (int r = 0; r < 4; r++) mx = fmaxf(mx, s[jt][r]);
        mx = fmaxf(mx, __shfl_xor(mx, 16));
        mx = fmaxf(mx, __shfl_xor(mx, 32));

        float m_new, alpha;
        if (__all(mx - m_i <= 8.f)) {           // T13 defer-rescale
            m_new = m_i; alpha = 1.f;
        } else {
            m_new = fmaxf(m_i, mx);
            alpha = exp2f(m_i - m_new);
#pragma unroll
            for (int ct = 0; ct < 8; ct++) acc[ct] *= alpha;
        }

        float sum = 0.f;
        const int prow = (16 * w + lm) * 128;
#pragma unroll
        for (int jt = 0; jt < 8; jt++) {
            const float p0f = exp2f(s[jt][0] - m_new);
            const float p1f = exp2f(s[jt][1] - m_new);
            const float p2f = exp2f(s[jt][2] - m_new);
            const float p3f = exp2f(s[jt][3] - m_new);
            sum += (p0f + p1f) + (p2f + p3f);
            uint2 pk;
            pk.x = cvt_pk_bf16(p0f, p1f);
            pk.y = cvt_pk_bf16(p2f, p3f);
            const int g = (2 * jt + (lg >> 1)) ^ lm;   // swizzled granule
            *(uint2*)&P_l[prow + g * 8 + (lg & 1) * 4] = pk;
        }
        sum += __shfl_xor(sum, 16);
        sum += __shfl_xor(sum, 32);
        l_i = l_i * alpha + sum;
        m_i = m_new;

        // ---- PV: acc[ct] += v-tile(ct) . P^T (same-wave LDS, lgkmcnt-ordered) ----
#pragma unroll
        for (int ks = 0; ks < 4; ks++) {
            const int g = (4 * ks + lg) ^ lm;          // same swizzle both reads
            const bf16x8 pf = *(const bf16x8*)&P_l[prow + g * 8];
#pragma unroll
            for (int ct = 0; ct < 8; ct++) {
                const bf16x8 vf = *(const bf16x8*)&v_l[(ct * 16 + lm) * 128 + g * 8];
                acc[ct] = __builtin_amdgcn_mfma_f32_16x16x32_bf16(vf, pf, acc[ct], 0, 0, 0);
            }
        }
    }

    // ---- epilogue: out = gamma * (acc / l) + x ----
    const float linv = 1.f / l_i;
    const float gm = gamma[0];
    const int i = 16 * w + lm;
#pragma unroll
    for (int ct = 0; ct < 8; ct++) {
#pragma unroll
        for (int r = 0; r < 4; r++) {
            const int c = ct * 16 + lg * 4 + r;
            const size_t off = ((size_t)(b * CCH + c)) * HW + i0 + i;
            out[off] = gm * (acc[ct][r] * linv) + x[off];
        }
    }
}

extern "C" void kernel_launch(void* const* d_in, const int* in_sizes, int n_in,
                              void* d_out, int out_size, void* d_ws, size_t ws_size,
                              hipStream_t stream)
{
    const float* x     = (const float*)d_in[0];
    const float* Wq    = (const float*)d_in[1];
    const float* bq    = (const float*)d_in[2];
    const float* Wk    = (const float*)d_in[3];
    const float* bk    = (const float*)d_in[4];
    const float* Wv    = (const float*)d_in[5];
    const float* bv    = (const float*)d_in[6];
    const float* gamma = (const float*)d_in[7];
    float* out = (float*)d_out;

    ushort* qT = (ushort*)d_ws;                          // [8][4096][16] bf16 (x log2e)
    ushort* kT = qT + (size_t)BATCH * HW * DQK;          // [8][4096][16] bf16
    ushort* v  = kT + (size_t)BATCH * HW * DQK;          // [8][128][4096] bf16

    qkv_kernel<<<dim3(BATCH * (HW / 64)), dim3(256), 0, stream>>>(
        x, Wq, bq, Wk, bk, Wv, bv, qT, kT, v);
    attn_kernel<<<dim3(BATCH * (HW / 64)), dim3(256), 0, stream>>>(
        qT, kT, v, x, gamma, out);
}